// Round 2
// baseline (323457.202 us; speedup 1.0000x reference)
//
#include <hip/hip_runtime.h>
#include <math.h>

#define BB 128
#define NTR 16384
#define DD 1024
#define PN (BB*NTR)     // 2097152
#define CN (BB*DD)      // 131072
#define HN (NTR*DD)     // 16777216

typedef short bf16x8 __attribute__((ext_vector_type(8)));
typedef float f32x4v __attribute__((ext_vector_type(4)));

// ---------------- bf16 split helpers ----------------
__device__ __forceinline__ ushort f2bf(float f) {
  uint u = __float_as_uint(f);
  return (ushort)((u + 0x7FFFu + ((u >> 16) & 1u)) >> 16);   // RNE
}
__device__ __forceinline__ float bf2f(ushort h) { return __uint_as_float(((uint)h) << 16); }
__device__ __forceinline__ void split3(float f, ushort& a, ushort& b, ushort& c) {
  a = f2bf(f); float r1 = f - bf2f(a);     // exact (Sterbenz zone)
  b = f2bf(r1); float r2 = r1 - bf2f(b);   // exact
  c = f2bf(r2);
}

// ---------------- one-time: split H into hi/mid/lo + transposed copies ----------------
// grid (16 n-tiles, 256 k-tiles), block 256; tile 64(k) x 64(n)
__global__ __launch_bounds__(256) void k_prep(const float* __restrict__ H,
    ushort* __restrict__ H0, ushort* __restrict__ H1, ushort* __restrict__ H2,
    ushort* __restrict__ T0, ushort* __restrict__ T1, ushort* __restrict__ T2)
{
  __shared__ float t[64][65];
  const int n0 = blockIdx.x * 64, k0 = blockIdx.y * 64;
  const int tid = threadIdx.x;
  {
    const int r = tid >> 2, c = (tid & 3) * 16;
    const float* src = H + (size_t)(k0 + r) * DD + n0 + c;
    ushort h0[16], h1[16], h2[16];
#pragma unroll
    for (int e = 0; e < 16; ++e) {
      float x = src[e]; t[r][c + e] = x;
      split3(x, h0[e], h1[e], h2[e]);
    }
    const size_t ob = (size_t)(k0 + r) * DD + n0 + c;
#pragma unroll
    for (int e = 0; e < 16; ++e) { H0[ob+e]=h0[e]; H1[ob+e]=h1[e]; H2[ob+e]=h2[e]; }
  }
  __syncthreads();
  {
    const int n = tid >> 2, kc = (tid & 3) * 16;
    ushort h0[16], h1[16], h2[16];
#pragma unroll
    for (int e = 0; e < 16; ++e) split3(t[kc + e][n], h0[e], h1[e], h2[e]);
    const size_t ob = (size_t)(n0 + n) * NTR + k0 + kc;
#pragma unroll
    for (int e = 0; e < 16; ++e) { T0[ob+e]=h0[e]; T1[ob+e]=h1[e]; T2[ob+e]=h2[e]; }
  }
}

// ---------------- softmax + w-splits ----------------
__global__ __launch_bounds__(256) void k_softmax(const float* __restrict__ p,
    float* __restrict__ wfp,
    ushort* __restrict__ w0, ushort* __restrict__ w1, ushort* __restrict__ w2)
{
  const int row = blockIdx.x, tid = threadIdx.x;
  const float* pr = p + (size_t)row * NTR;
  float x[64];
  float mx = -INFINITY;
#pragma unroll
  for (int i = 0; i < 64; ++i) { x[i] = pr[i*256 + tid]; mx = fmaxf(mx, x[i]); }
  __shared__ float red[256];
  red[tid] = mx; __syncthreads();
  for (int s = 128; s > 0; s >>= 1) { if (tid < s) red[tid] = fmaxf(red[tid], red[tid+s]); __syncthreads(); }
  mx = red[0]; __syncthreads();
  float sum = 0.f;
#pragma unroll
  for (int i = 0; i < 64; ++i) { x[i] = expf(x[i] - mx); sum += x[i]; }
  red[tid] = sum; __syncthreads();
  for (int s = 128; s > 0; s >>= 1) { if (tid < s) red[tid] += red[tid+s]; __syncthreads(); }
  const float inv = 1.0f / red[0];
  const size_t rb = (size_t)row * NTR;
#pragma unroll
  for (int i = 0; i < 64; ++i) {
    const float val = x[i] * inv;
    const size_t idx = rb + i*256 + tid;
    if (wfp) wfp[idx] = val;
    ushort a, b, c; split3(val, a, b, c);
    w0[idx] = a; w1[idx] = b; w2[idx] = c;
  }
}

// ---------------- 6-product split-bf16 GEMM (emulated fp32) ----------------
// C(partial) = A * B^T_stored : A [128 x K] row-major (lda), B stored [Ncols x K] row-major (ldb)
// block tile 128x128, 4 waves (2x2), wave tile 64x64, K-step 32, mfma 16x16x32
// grid: (N/128, K/kchunk); slab by at C + by*128*ldc
__global__ __launch_bounds__(256, 2) void k_gemm6(
    const ushort* __restrict__ A0, const ushort* __restrict__ A1, const ushort* __restrict__ A2,
    const ushort* __restrict__ B0, const ushort* __restrict__ B1, const ushort* __restrict__ B2,
    float* __restrict__ C, int lda, int ldb, int ldc, int kchunk)
{
  __shared__ ushort lds[24576];   // A: 3*[128][32] = 12288, B: 3*[128][32] = 12288
  const int tid = threadIdx.x;
  const int lane = tid & 63, wid = tid >> 6;
  const int wm = (wid >> 1) * 64, wn = (wid & 1) * 64;
  const int n0 = blockIdx.x * 128;
  const int kbase = blockIdx.y * kchunk;
  C += (size_t)blockIdx.y * 128 * ldc;

  const ushort* Ap[3] = {A0, A1, A2};
  const ushort* Bp[3] = {B0, B1, B2};

  f32x4v acc[4][4];
#pragma unroll
  for (int i = 0; i < 4; ++i)
#pragma unroll
    for (int j = 0; j < 4; ++j) acc[i][j] = (f32x4v){0.f, 0.f, 0.f, 0.f};

  const int ksteps = kchunk >> 5;
  for (int kt = 0; kt < ksteps; ++kt) {
    const int kpos = kbase + (kt << 5);
    // stage A: 1536 16B-chunks; layout lds[s*4096 + row*32 + slot*8], source slot XOR-swizzled
#pragma unroll
    for (int c = 0; c < 6; ++c) {
      const int L = c*256 + tid;
      const int s = L >> 9, rr = L & 511;
      const int row = rr >> 2, slot = rr & 3;
      const int sl = slot ^ ((row >> 1) & 3);
      const ushort* src = Ap[s] + (size_t)row * lda + kpos + (sl << 3);
      __builtin_amdgcn_global_load_lds((const __attribute__((address_space(1))) void*)src,
          (__attribute__((address_space(3))) void*)&lds[(size_t)(c*256 + (wid << 6)) * 8], 16, 0, 0);
    }
#pragma unroll
    for (int c = 0; c < 6; ++c) {
      const int L = c*256 + tid;
      const int s = L >> 9, rr = L & 511;
      const int row = rr >> 2, slot = rr & 3;
      const int sl = slot ^ ((row >> 1) & 3);
      const ushort* src = Bp[s] + (size_t)(n0 + row) * ldb + kpos + (sl << 3);
      __builtin_amdgcn_global_load_lds((const __attribute__((address_space(1))) void*)src,
          (__attribute__((address_space(3))) void*)&lds[12288 + (size_t)(c*256 + (wid << 6)) * 8], 16, 0, 0);
    }
    __syncthreads();

    bf16x8 bf[3][4];
#pragma unroll
    for (int s = 0; s < 3; ++s)
#pragma unroll
      for (int j = 0; j < 4; ++j) {
        const int n = wn + j*16 + (lane & 15);
        const int sl = (lane >> 4) ^ ((n >> 1) & 3);
        bf[s][j] = *(const bf16x8*)&lds[12288 + s*4096 + n*32 + sl*8];
      }
#pragma unroll
    for (int sa = 0; sa < 3; ++sa) {
      bf16x8 af[4];
#pragma unroll
      for (int i = 0; i < 4; ++i) {
        const int mrow = wm + i*16 + (lane & 15);
        const int sl = (lane >> 4) ^ ((mrow >> 1) & 3);
        af[i] = *(const bf16x8*)&lds[sa*4096 + mrow*32 + sl*8];
      }
#pragma unroll
      for (int sb = 0; sb < 3 - sa; ++sb)
#pragma unroll
        for (int i = 0; i < 4; ++i)
#pragma unroll
          for (int j = 0; j < 4; ++j)
            acc[i][j] = __builtin_amdgcn_mfma_f32_16x16x32_bf16(af[i], bf[sb][j], acc[i][j], 0, 0, 0);
    }
    __syncthreads();
  }
  // epilogue: D col = lane&15, row = (lane>>4)*4 + reg
#pragma unroll
  for (int i = 0; i < 4; ++i) {
    const int rbase = wm + i*16 + ((lane >> 4) << 2);
#pragma unroll
    for (int j = 0; j < 4; ++j) {
      const int cg = n0 + wn + j*16 + (lane & 15);
#pragma unroll
      for (int r = 0; r < 4; ++r)
        C[(size_t)(rbase + r) * ldc + cg] = acc[i][j][r];
    }
  }
}

// ---------------- S2 = 2*(sum_64 Cpart - h), emit splits ----------------
__global__ __launch_bounds__(256) void k_reduce_S(const float* __restrict__ X,
    const float* __restrict__ h,
    ushort* __restrict__ s0, ushort* __restrict__ s1, ushort* __restrict__ s2)
{
  const size_t off = ((size_t)blockIdx.x * 256 + threadIdx.x) * 4;
  float4 s = make_float4(0.f, 0.f, 0.f, 0.f);
  for (int k = 0; k < 64; ++k) {
    const float4 c = *(const float4*)(X + (size_t)k * CN + off);
    s.x += c.x; s.y += c.y; s.z += c.z; s.w += c.w;
  }
  const float4 hh = *(const float4*)(h + off);
  float vals[4] = {2.f*(s.x-hh.x), 2.f*(s.y-hh.y), 2.f*(s.z-hh.z), 2.f*(s.w-hh.w)};
  ushort a[4], b[4], c4[4];
#pragma unroll
  for (int e = 0; e < 4; ++e) split3(vals[e], a[e], b[e], c4[e]);
  *(ushort4*)(s0 + off) = make_ushort4(a[0], a[1], a[2], a[3]);
  *(ushort4*)(s1 + off) = make_ushort4(b[0], b[1], b[2], b[3]);
  *(ushort4*)(s2 + off) = make_ushort4(c4[0], c4[1], c4[2], c4[3]);
}

// ---------------- r[row] = sum_j w[row][j] * u[row][j], u = sum of 4 dp slabs ----------------
__global__ __launch_bounds__(256) void k_rdot(const float* __restrict__ X,
    const ushort* __restrict__ w0, const ushort* __restrict__ w1, const ushort* __restrict__ w2,
    float* __restrict__ r)
{
  const int row = blockIdx.x, tid = threadIdx.x;
  const size_t rb = (size_t)row * NTR;
  float sum = 0.f;
  for (int c = 0; c < 16; ++c) {
    const size_t off = rb + (size_t)c * 1024 + tid * 4;
    float4 u  = *(const float4*)(X + off);
    const float4 u1 = *(const float4*)(X + (size_t)PN + off);
    const float4 u2 = *(const float4*)(X + (size_t)2*PN + off);
    const float4 u3 = *(const float4*)(X + (size_t)3*PN + off);
    u.x += u1.x + u2.x + u3.x; u.y += u1.y + u2.y + u3.y;
    u.z += u1.z + u2.z + u3.z; u.w += u1.w + u2.w + u3.w;
    const ushort4 a = *(const ushort4*)(w0 + off);
    const ushort4 b = *(const ushort4*)(w1 + off);
    const ushort4 d = *(const ushort4*)(w2 + off);
    sum += (bf2f(a.x)+bf2f(b.x)+bf2f(d.x)) * u.x
         + (bf2f(a.y)+bf2f(b.y)+bf2f(d.y)) * u.y
         + (bf2f(a.z)+bf2f(b.z)+bf2f(d.z)) * u.z
         + (bf2f(a.w)+bf2f(b.w)+bf2f(d.w)) * u.w;
  }
  __shared__ float red[256];
  red[tid] = sum; __syncthreads();
  for (int s = 128; s > 0; s >>= 1) { if (tid < s) red[tid] += red[tid+s]; __syncthreads(); }
  if (tid == 0) r[row] = red[0];
}

// ---------------- Adam ----------------
__global__ __launch_bounds__(256) void k_adam(float* __restrict__ p,
    float* __restrict__ m, float* __restrict__ v,
    const ushort* __restrict__ w0, const ushort* __restrict__ w1, const ushort* __restrict__ w2,
    const float* __restrict__ X, const float* __restrict__ r, float bc1, float bc2)
{
  const int bid = blockIdx.x;
  const float rr = r[bid >> 3];
  const size_t base = (size_t)bid * 2048 + threadIdx.x * 4;
#pragma unroll
  for (int part = 0; part < 2; ++part) {
    const size_t off = base + part * 1024;
    float4 u  = *(const float4*)(X + off);
    const float4 u1 = *(const float4*)(X + (size_t)PN + off);
    const float4 u2 = *(const float4*)(X + (size_t)2*PN + off);
    const float4 u3 = *(const float4*)(X + (size_t)3*PN + off);
    u.x += u1.x + u2.x + u3.x; u.y += u1.y + u2.y + u3.y;
    u.z += u1.z + u2.z + u3.z; u.w += u1.w + u2.w + u3.w;
    const ushort4 a = *(const ushort4*)(w0 + off);
    const ushort4 b = *(const ushort4*)(w1 + off);
    const ushort4 d = *(const ushort4*)(w2 + off);
    float wv[4] = {bf2f(a.x)+bf2f(b.x)+bf2f(d.x), bf2f(a.y)+bf2f(b.y)+bf2f(d.y),
                   bf2f(a.z)+bf2f(b.z)+bf2f(d.z), bf2f(a.w)+bf2f(b.w)+bf2f(d.w)};
    float uu[4] = {u.x, u.y, u.z, u.w};
    float4 p4 = *(float4*)(p + off);
    float4 m4 = *(float4*)(m + off);
    float4 v4 = *(float4*)(v + off);
    float* pp = (float*)&p4; float* mm = (float*)&m4; float* vv = (float*)&v4;
#pragma unroll
    for (int e = 0; e < 4; ++e) {
      const float g  = wv[e] * (uu[e] - rr);
      const float mn = 0.9f*mm[e] + 0.1f*g;
      const float vn = 0.999f*vv[e] + 0.001f*(g*g);
      const float mh = mn / bc1, vh = vn / bc2;
      pp[e] = pp[e] - 1e-3f * mh / (sqrtf(vh) + 1e-8f);
      mm[e] = mn; vv[e] = vn;
    }
    *(float4*)(p + off) = p4;
    *(float4*)(m + off) = m4;
    *(float4*)(v + off) = v4;
  }
}

// ================= fallback (round-0 fp32 path, proven) =================
#define SPLITK_FB 16
#define KCHUNK_FB (NTR/SPLITK_FB)
__global__ __launch_bounds__(256) void k_softmax_fb(const float* __restrict__ p, float* __restrict__ w) {
  const int row = blockIdx.x, tid = threadIdx.x;
  const float* pr = p + (size_t)row * NTR;
  float x[64]; float mx = -INFINITY;
#pragma unroll
  for (int i = 0; i < 64; ++i) { x[i] = pr[i*256 + tid]; mx = fmaxf(mx, x[i]); }
  __shared__ float red[256];
  red[tid] = mx; __syncthreads();
  for (int s = 128; s > 0; s >>= 1) { if (tid < s) red[tid] = fmaxf(red[tid], red[tid+s]); __syncthreads(); }
  mx = red[0]; __syncthreads();
  float sum = 0.f;
#pragma unroll
  for (int i = 0; i < 64; ++i) { x[i] = expf(x[i] - mx); sum += x[i]; }
  red[tid] = sum; __syncthreads();
  for (int s = 128; s > 0; s >>= 1) { if (tid < s) red[tid] += red[tid+s]; __syncthreads(); }
  const float inv = 1.0f / red[0];
  float* wr = w + (size_t)row * NTR;
#pragma unroll
  for (int i = 0; i < 64; ++i) wr[i*256 + tid] = x[i] * inv;
}
__global__ __launch_bounds__(128) void k_fwd_fb(const float* __restrict__ w, const float* __restrict__ H,
                                                float* __restrict__ Cpart) {
  const int nt = blockIdx.x, ks = blockIdx.y, tid = threadIdx.x;
  __shared__ float As[8][128]; __shared__ float Bs[8][64];
  const int tm = tid >> 3, tn = tid & 7; const int m0 = tm*8, n0 = tn*8;
  float acc[8][8];
#pragma unroll
  for (int i = 0; i < 8; ++i)
#pragma unroll
    for (int j = 0; j < 8; ++j) acc[i][j] = 0.f;
  const int kbase = ks * KCHUNK_FB;
  for (int kk = 0; kk < KCHUNK_FB; kk += 8) {
#pragma unroll
    for (int t = 0; t < 2; ++t) {
      const int tau = tid + t*128, mm = tau >> 1, q = tau & 1;
      const float4 a4 = *(const float4*)(w + (size_t)mm*NTR + kbase + kk + q*4);
      As[q*4+0][mm]=a4.x; As[q*4+1][mm]=a4.y; As[q*4+2][mm]=a4.z; As[q*4+3][mm]=a4.w;
    }
    { const int r = tid >> 4, c = (tid & 15) * 4;
      *(float4*)&Bs[r][c] = *(const float4*)(H + (size_t)(kbase+kk+r)*DD + nt*64 + c); }
    __syncthreads();
#pragma unroll
    for (int k = 0; k < 8; ++k) {
      float a[8], b[8];
      *(float4*)&a[0] = *(const float4*)&As[k][m0]; *(float4*)&a[4] = *(const float4*)&As[k][m0+4];
      *(float4*)&b[0] = *(const float4*)&Bs[k][n0]; *(float4*)&b[4] = *(const float4*)&Bs[k][n0+4];
#pragma unroll
      for (int i = 0; i < 8; ++i)
#pragma unroll
        for (int j = 0; j < 8; ++j) acc[i][j] = fmaf(a[i], b[j], acc[i][j]);
    }
    __syncthreads();
  }
  float* Cp = Cpart + (size_t)ks*CN;
#pragma unroll
  for (int i = 0; i < 8; ++i) {
    float* dst = Cp + (size_t)(m0+i)*DD + nt*64 + n0;
    *(float4*)dst     = make_float4(acc[i][0],acc[i][1],acc[i][2],acc[i][3]);
    *(float4*)(dst+4) = make_float4(acc[i][4],acc[i][5],acc[i][6],acc[i][7]);
  }
}
__global__ __launch_bounds__(256) void k_reduce_S_fb(const float* __restrict__ Cpart,
                                                     const float* __restrict__ h, float* __restrict__ S2) {
  const int idx = blockIdx.x*256 + threadIdx.x;
  float s = 0.f;
#pragma unroll
  for (int k = 0; k < SPLITK_FB; ++k) s += Cpart[(size_t)k*CN + idx];
  S2[idx] = 2.0f * (s - h[idx]);
}
__global__ __launch_bounds__(128) void k_bwd_fb(const float* __restrict__ S2, const float* __restrict__ H,
                                                const float* __restrict__ w, float* __restrict__ dw,
                                                float* __restrict__ rpart) {
  const int bn = blockIdx.x, tid = threadIdx.x;
  __shared__ float As[8][128]; __shared__ float Bs[8][64]; __shared__ float rbuf[128][9];
  const int tm = tid >> 3, tn = tid & 7; const int m0 = tm*8, n0 = tn*8;
  const int col0 = bn * 64;
  float acc[8][8];
#pragma unroll
  for (int i = 0; i < 8; ++i)
#pragma unroll
    for (int j = 0; j < 8; ++j) acc[i][j] = 0.f;
  for (int kk = 0; kk < DD; kk += 8) {
#pragma unroll
    for (int t = 0; t < 2; ++t) {
      const int tau = tid + t*128, mm = tau >> 1, q = tau & 1;
      const float4 a4 = *(const float4*)(S2 + (size_t)mm*DD + kk + q*4);
      As[q*4+0][mm]=a4.x; As[q*4+1][mm]=a4.y; As[q*4+2][mm]=a4.z; As[q*4+3][mm]=a4.w;
    }
    { const int jj = tid >> 1, q = tid & 1;
      const float4 b4 = *(const float4*)(H + (size_t)(col0+jj)*DD + kk + q*4);
      Bs[q*4+0][jj]=b4.x; Bs[q*4+1][jj]=b4.y; Bs[q*4+2][jj]=b4.z; Bs[q*4+3][jj]=b4.w; }
    __syncthreads();
#pragma unroll
    for (int k = 0; k < 8; ++k) {
      float a[8], b[8];
      *(float4*)&a[0] = *(const float4*)&As[k][m0]; *(float4*)&a[4] = *(const float4*)&As[k][m0+4];
      *(float4*)&b[0] = *(const float4*)&Bs[k][n0]; *(float4*)&b[4] = *(const float4*)&Bs[k][n0+4];
#pragma unroll
      for (int i = 0; i < 8; ++i)
#pragma unroll
        for (int j = 0; j < 8; ++j) acc[i][j] = fmaf(a[i], b[j], acc[i][j]);
    }
    __syncthreads();
  }
#pragma unroll
  for (int i = 0; i < 8; ++i) {
    float* dst = dw + (size_t)(m0+i)*NTR + col0 + n0;
    *(float4*)dst     = make_float4(acc[i][0],acc[i][1],acc[i][2],acc[i][3]);
    *(float4*)(dst+4) = make_float4(acc[i][4],acc[i][5],acc[i][6],acc[i][7]);
    const float* wsrc = w + (size_t)(m0+i)*NTR + col0 + n0;
    const float4 w0 = *(const float4*)wsrc; const float4 w1 = *(const float4*)(wsrc+4);
    rbuf[m0+i][tn] = w0.x*acc[i][0]+w0.y*acc[i][1]+w0.z*acc[i][2]+w0.w*acc[i][3]
                   + w1.x*acc[i][4]+w1.y*acc[i][5]+w1.z*acc[i][6]+w1.w*acc[i][7];
  }
  __syncthreads();
  if (tid < 128) {
    float s = 0.f;
#pragma unroll
    for (int t = 0; t < 8; ++t) s += rbuf[tid][t];
    rpart[(size_t)bn*128 + tid] = s;
  }
}
__global__ __launch_bounds__(256) void k_adam_fb(float* __restrict__ p, float* __restrict__ m,
    float* __restrict__ v, const float* __restrict__ w, const float* __restrict__ dw,
    const float* __restrict__ rpart, float bc1, float bc2) {
  const int row = blockIdx.x >> 3, chunk = blockIdx.x & 7;
  const int tid = threadIdx.x;
  __shared__ float red[256];
  red[tid] = rpart[(size_t)tid*128 + row]; __syncthreads();
  for (int s = 128; s > 0; s >>= 1) { if (tid < s) red[tid] += red[tid+s]; __syncthreads(); }
  const float r = red[0];
  const size_t base = (size_t)row*NTR + (size_t)chunk*2048;
#pragma unroll
  for (int part = 0; part < 2; ++part) {
    const size_t off = base + part*1024 + tid*4;
    const float4 w4 = *(const float4*)(w+off);
    const float4 d4 = *(const float4*)(dw+off);
    float4 p4 = *(float4*)(p+off); float4 m4 = *(float4*)(m+off); float4 v4 = *(float4*)(v+off);
    float g, mn, vn, mh, vh;
#define ADAM_C(c) \
    g  = w4.c * (d4.c - r); mn = 0.9f*m4.c + 0.1f*g; vn = 0.999f*v4.c + 0.001f*(g*g); \
    mh = mn / bc1; vh = vn / bc2; p4.c = p4.c - 1e-3f * mh / (sqrtf(vh) + 1e-8f); \
    m4.c = mn; v4.c = vn;
    ADAM_C(x) ADAM_C(y) ADAM_C(z) ADAM_C(w)
#undef ADAM_C
    *(float4*)(p+off) = p4; *(float4*)(m+off) = m4; *(float4*)(v+off) = v4;
  }
}

extern "C" void kernel_launch(void* const* d_in, const int* in_sizes, int n_in,
                              void* d_out, int out_size, void* d_ws, size_t ws_size,
                              hipStream_t stream) {
  const float* h = (const float*)d_in[0];
  const float* H = (const float*)d_in[1];
  (void)in_sizes; (void)n_in; (void)out_size;
  const int n_epoch = 1000;

  const size_t floats  = (size_t)3*PN + (size_t)4*PN + 256;
  const size_t ushorts = (size_t)3*PN + (size_t)3*CN + (size_t)6*HN;
  const size_t NEED = floats*4 + ushorts*2;   // 273,417,216 B

  if (ws_size >= NEED) {
    float* p  = (float*)d_ws;
    float* m  = p + PN;
    float* v  = m + PN;
    float* X  = v + PN;                 // 4*PN: fwd = 64 slabs of CN; bwd = 4 slabs of PN
    float* r  = X + (size_t)4*PN;       // 256
    ushort* U  = (ushort*)(r + 256);
    ushort* w0 = U,            *w1 = w0 + PN, *w2 = w1 + PN;
    ushort* s0 = w2 + PN,      *s1 = s0 + CN, *s2 = s1 + CN;
    ushort* H0 = s2 + CN,      *H1 = H0 + HN, *H2 = H1 + HN;
    ushort* T0 = H2 + HN,      *T1 = T0 + HN, *T2 = T1 + HN;

    hipMemsetAsync(p, 0, (size_t)3*PN*sizeof(float), stream);
    k_prep<<<dim3(16, 256), 256, 0, stream>>>(H, H0, H1, H2, T0, T1, T2);

    for (int s = 1; s <= n_epoch; ++s) {
      k_softmax<<<BB, 256, 0, stream>>>(p, nullptr, w0, w1, w2);
      k_gemm6<<<dim3(8, 64), 256, 0, stream>>>(w0, w1, w2, T0, T1, T2, X, NTR, NTR, DD, 256);
      k_reduce_S<<<CN/1024, 256, 0, stream>>>(X, h, s0, s1, s2);
      k_gemm6<<<dim3(128, 4), 256, 0, stream>>>(s0, s1, s2, H0, H1, H2, X, DD, DD, NTR, 256);
      k_rdot<<<BB, 256, 0, stream>>>(X, w0, w1, w2, r);
      const float bc1 = 1.0f - powf(0.9f,   (float)s);
      const float bc2 = 1.0f - powf(0.999f, (float)s);
      k_adam<<<1024, 256, 0, stream>>>(p, m, v, w0, w1, w2, X, r, bc1, bc2);
    }
    k_softmax<<<BB, 256, 0, stream>>>(p, (float*)d_out, w0, w1, w2);
  } else {
    // fallback: round-0 fp32 path (needs ~51 MB)
    float* ws = (float*)d_ws;
    float* p  = ws;
    float* m  = p + PN;
    float* v  = m + PN;
    float* w  = v + PN;
    float* dw = w + PN;
    float* Cp = dw + PN;
    float* S2 = Cp + (size_t)SPLITK_FB*CN;
    float* rp = S2 + CN;

    hipMemsetAsync(p, 0, (size_t)3*PN*sizeof(float), stream);
    for (int s = 1; s <= n_epoch; ++s) {
      k_softmax_fb<<<BB, 256, 0, stream>>>(p, w);
      k_fwd_fb<<<dim3(16, SPLITK_FB), 128, 0, stream>>>(w, H, Cp);
      k_reduce_S_fb<<<CN/256, 256, 0, stream>>>(Cp, h, S2);
      k_bwd_fb<<<256, 128, 0, stream>>>(S2, H, w, dw, rp);
      const float bc1 = 1.0f - powf(0.9f,   (float)s);
      const float bc2 = 1.0f - powf(0.999f, (float)s);
      k_adam_fb<<<BB*8, 256, 0, stream>>>(p, m, v, w, dw, rp, bc1, bc2);
    }
    k_softmax_fb<<<BB, 256, 0, stream>>>(p, (float*)d_out);
  }
}

// Round 6
// 143223.035 us; speedup vs baseline: 2.2584x; 2.2584x over previous
//
#include <hip/hip_runtime.h>
#include <math.h>

#define BB 128
#define NTR 16384
#define DD 1024
#define PN (BB*NTR)     // 2097152
#define CN (BB*DD)      // 131072
#define HN (NTR*DD)     // 16777216
#define FWD_SLABS 32    // fwd split-K: 32 slabs of CN = 2*PN floats
#define BWD_SLABS 2     // bwd split-K: 2 slabs of PN

typedef short bf16x8 __attribute__((ext_vector_type(8)));
typedef float f32x4v __attribute__((ext_vector_type(4)));

// ---------------- bf16 split helpers ----------------
__device__ __forceinline__ ushort f2bf(float f) {
  uint u = __float_as_uint(f);
  return (ushort)((u + 0x7FFFu + ((u >> 16) & 1u)) >> 16);   // RNE
}
__device__ __forceinline__ float bf2f(ushort h) { return __uint_as_float(((uint)h) << 16); }
// exact 3-way split: f == a + b + c
__device__ __forceinline__ void split3(float f, ushort& a, ushort& b, ushort& c) {
  a = f2bf(f); float r1 = f - bf2f(a);
  b = f2bf(r1); float r2 = r1 - bf2f(b);
  c = f2bf(r2);
}

// ---------------- one-time: split H (row-major) ----------------
__global__ __launch_bounds__(256) void k_prep(const float* __restrict__ H,
    ushort* __restrict__ H0, ushort* __restrict__ H1, ushort* __restrict__ H2)
{
  const size_t i = ((size_t)blockIdx.x * 256 + threadIdx.x) * 4;
  const float4 x = *(const float4*)(H + i);
  ushort a[4], b[4], c[4];
  split3(x.x, a[0], b[0], c[0]); split3(x.y, a[1], b[1], c[1]);
  split3(x.z, a[2], b[2], c[2]); split3(x.w, a[3], b[3], c[3]);
  *(ushort4*)(H0 + i) = make_ushort4(a[0], a[1], a[2], a[3]);
  *(ushort4*)(H1 + i) = make_ushort4(b[0], b[1], b[2], b[3]);
  *(ushort4*)(H2 + i) = make_ushort4(c[0], c[1], c[2], c[3]);
}

// ---------------- softmax: p -> w (fp32) ----------------
__global__ __launch_bounds__(256) void k_softmax_f(const float* __restrict__ p,
                                                   float* __restrict__ w) {
  const int row = blockIdx.x, tid = threadIdx.x;
  const float* pr = p + (size_t)row * NTR;
  float x[64]; float mx = -INFINITY;
#pragma unroll
  for (int i = 0; i < 64; ++i) { x[i] = pr[i*256 + tid]; mx = fmaxf(mx, x[i]); }
  __shared__ float red[256];
  red[tid] = mx; __syncthreads();
  for (int s = 128; s > 0; s >>= 1) { if (tid < s) red[tid] = fmaxf(red[tid], red[tid+s]); __syncthreads(); }
  mx = red[0]; __syncthreads();
  float sum = 0.f;
#pragma unroll
  for (int i = 0; i < 64; ++i) { x[i] = expf(x[i] - mx); sum += x[i]; }
  red[tid] = sum; __syncthreads();
  for (int s = 128; s > 0; s >>= 1) { if (tid < s) red[tid] += red[tid+s]; __syncthreads(); }
  const float inv = 1.0f / red[0];
  float* wr = w + (size_t)row * NTR;
#pragma unroll
  for (int i = 0; i < 64; ++i) wr[i*256 + tid] = x[i] * inv;
}

// ---------------- VALU fp32 forward: C(slab) = w[128 x 512k] @ H[512k x 1024] ----------------
// grid (16 n-tiles of 64, 32 k-slabs), block 256, tile 128x64, micro 8x4
__global__ __launch_bounds__(256) void k_fwd_v(const float* __restrict__ w,
    const float* __restrict__ H, float* __restrict__ Cp)
{
  const int nt = blockIdx.x, tid = threadIdx.x;
  const int kbase = blockIdx.y * 512;
  Cp += (size_t)blockIdx.y * CN;
  __shared__ float As[8][128];
  __shared__ float Bs[8][64];
  const int tm = tid >> 4, tn = tid & 15;
  const int m0 = tm * 8, n0 = tn * 4;
  float acc[8][4];
#pragma unroll
  for (int i = 0; i < 8; ++i)
#pragma unroll
    for (int j = 0; j < 4; ++j) acc[i][j] = 0.f;
  for (int kk = 0; kk < 512; kk += 8) {
    {
      const int mm = tid >> 1, q = tid & 1;
      const float4 a4 = *(const float4*)(w + (size_t)mm*NTR + kbase + kk + q*4);
      As[q*4+0][mm]=a4.x; As[q*4+1][mm]=a4.y; As[q*4+2][mm]=a4.z; As[q*4+3][mm]=a4.w;
    }
    if (tid < 128) {
      const int r = tid >> 4, c = (tid & 15) * 4;
      *(float4*)&Bs[r][c] = *(const float4*)(H + (size_t)(kbase+kk+r)*DD + nt*64 + c);
    }
    __syncthreads();
#pragma unroll
    for (int k = 0; k < 8; ++k) {
      float a[8], b[4];
      *(float4*)&a[0] = *(const float4*)&As[k][m0];
      *(float4*)&a[4] = *(const float4*)&As[k][m0+4];
      *(float4*)&b[0] = *(const float4*)&Bs[k][n0];
#pragma unroll
      for (int i = 0; i < 8; ++i)
#pragma unroll
        for (int j = 0; j < 4; ++j) acc[i][j] = fmaf(a[i], b[j], acc[i][j]);
    }
    __syncthreads();
  }
#pragma unroll
  for (int i = 0; i < 8; ++i)
    *(float4*)(Cp + (size_t)(m0+i)*DD + nt*64 + n0) =
        make_float4(acc[i][0], acc[i][1], acc[i][2], acc[i][3]);
}

// ---------------- S2 = 2*(sum_32 slabs - h), emit exact splits for bwd MFMA ----------------
__global__ __launch_bounds__(256) void k_reduce_S2s(const float* __restrict__ X,
    const float* __restrict__ h,
    ushort* __restrict__ s0, ushort* __restrict__ s1, ushort* __restrict__ s2)
{
  const size_t off = ((size_t)blockIdx.x * 256 + threadIdx.x) * 4;
  float4 s = make_float4(0.f, 0.f, 0.f, 0.f);
#pragma unroll 4
  for (int k = 0; k < FWD_SLABS; ++k) {
    const float4 c = *(const float4*)(X + (size_t)k * CN + off);
    s.x += c.x; s.y += c.y; s.z += c.z; s.w += c.w;
  }
  const float4 hh = *(const float4*)(h + off);
  float vals[4] = {2.f*(s.x-hh.x), 2.f*(s.y-hh.y), 2.f*(s.z-hh.z), 2.f*(s.w-hh.w)};
  ushort a[4], b[4], c4[4];
#pragma unroll
  for (int e = 0; e < 4; ++e) split3(vals[e], a[e], b[e], c4[e]);
  *(ushort4*)(s0 + off) = make_ushort4(a[0], a[1], a[2], a[3]);
  *(ushort4*)(s1 + off) = make_ushort4(b[0], b[1], b[2], b[3]);
  *(ushort4*)(s2 + off) = make_ushort4(c4[0], c4[1], c4[2], c4[3]);
}

// ---------------- BACKWARD 6-product MFMA GEMM: dw(slab) = S2[128 x 512k] @ H^T ----------------
// A = S2-splits (lda DD), B = H-splits stored [N x K] row-major (ldb DD)
// proven numerically irrelevant vs fp32 VALU bwd (R3 == R5 bit-identical)
__global__ __launch_bounds__(256, 2) void k_gemm6_bwd(
    const ushort* __restrict__ A0, const ushort* __restrict__ A1, const ushort* __restrict__ A2,
    const ushort* __restrict__ B0, const ushort* __restrict__ B1, const ushort* __restrict__ B2,
    float* __restrict__ C)
{
  __shared__ ushort lds[24576];
  const int tid = threadIdx.x;
  const int lane = tid & 63, wid = tid >> 6;
  const int wm = (wid >> 1) * 64, wn = (wid & 1) * 64;
  const int n0 = blockIdx.x * 128;
  const int kbase = blockIdx.y * 512;
  C += (size_t)blockIdx.y * PN;

  const ushort* Ap[3] = {A0, A1, A2};
  const ushort* Bp[3] = {B0, B1, B2};

  f32x4v acc[4][4];
#pragma unroll
  for (int i = 0; i < 4; ++i)
#pragma unroll
    for (int j = 0; j < 4; ++j) acc[i][j] = (f32x4v){0.f, 0.f, 0.f, 0.f};

  for (int kt = 0; kt < 16; ++kt) {
    const int kpos = kbase + (kt << 5);
#pragma unroll
    for (int c = 0; c < 6; ++c) {
      const int L = c*256 + tid;
      const int s = L >> 9, rr = L & 511;
      const int row = rr >> 2, slot = rr & 3;
      const int sl = slot ^ ((row >> 1) & 3);
      const ushort* src = Ap[s] + (size_t)row * DD + kpos + (sl << 3);
      __builtin_amdgcn_global_load_lds((const __attribute__((address_space(1))) void*)src,
          (__attribute__((address_space(3))) void*)&lds[(size_t)(c*256 + (wid << 6)) * 8], 16, 0, 0);
    }
#pragma unroll
    for (int c = 0; c < 6; ++c) {
      const int L = c*256 + tid;
      const int s = L >> 9, rr = L & 511;
      const int row = rr >> 2, slot = rr & 3;
      const int sl = slot ^ ((row >> 1) & 3);
      const ushort* src = Bp[s] + (size_t)(n0 + row) * DD + kpos + (sl << 3);
      __builtin_amdgcn_global_load_lds((const __attribute__((address_space(1))) void*)src,
          (__attribute__((address_space(3))) void*)&lds[12288 + (size_t)(c*256 + (wid << 6)) * 8], 16, 0, 0);
    }
    __syncthreads();

    bf16x8 bf[3][4];
#pragma unroll
    for (int s = 0; s < 3; ++s)
#pragma unroll
      for (int j = 0; j < 4; ++j) {
        const int n = wn + j*16 + (lane & 15);
        const int sl = (lane >> 4) ^ ((n >> 1) & 3);
        bf[s][j] = *(const bf16x8*)&lds[12288 + s*4096 + n*32 + sl*8];
      }
#pragma unroll
    for (int sa = 0; sa < 3; ++sa) {
      bf16x8 af[4];
#pragma unroll
      for (int i = 0; i < 4; ++i) {
        const int mrow = wm + i*16 + (lane & 15);
        const int sl = (lane >> 4) ^ ((mrow >> 1) & 3);
        af[i] = *(const bf16x8*)&lds[sa*4096 + mrow*32 + sl*8];
      }
#pragma unroll
      for (int sb = 0; sb < 3 - sa; ++sb)
#pragma unroll
        for (int i = 0; i < 4; ++i)
#pragma unroll
          for (int j = 0; j < 4; ++j)
            acc[i][j] = __builtin_amdgcn_mfma_f32_16x16x32_bf16(af[i], bf[sb][j], acc[i][j], 0, 0, 0);
    }
    __syncthreads();
  }
#pragma unroll
  for (int i = 0; i < 4; ++i) {
    const int rbase = wm + i*16 + ((lane >> 4) << 2);
#pragma unroll
    for (int j = 0; j < 4; ++j) {
      const int cg = n0 + wn + j*16 + (lane & 15);
#pragma unroll
      for (int r = 0; r < 4; ++r)
        C[(size_t)(rbase + r) * NTR + cg] = acc[i][j][r];
    }
  }
}

// ---------------- r[row] = sum_j w[row][j] * u[row][j] (u = 2 dw slabs) ----------------
__global__ __launch_bounds__(256) void k_rdot_f(const float* __restrict__ X,
    const float* __restrict__ w, float* __restrict__ r)
{
  const int row = blockIdx.x, tid = threadIdx.x;
  const size_t rb = (size_t)row * NTR;
  float sum = 0.f;
  for (int c = 0; c < 16; ++c) {
    const size_t off = rb + (size_t)c * 1024 + tid * 4;
    float4 u  = *(const float4*)(X + off);
    const float4 u1 = *(const float4*)(X + (size_t)PN + off);
    u.x += u1.x; u.y += u1.y; u.z += u1.z; u.w += u1.w;
    const float4 ww = *(const float4*)(w + off);
    sum += ww.x*u.x + ww.y*u.y + ww.z*u.z + ww.w*u.w;
  }
  __shared__ float red[256];
  red[tid] = sum; __syncthreads();
  for (int s = 128; s > 0; s >>= 1) { if (tid < s) red[tid] += red[tid+s]; __syncthreads(); }
  if (tid == 0) r[row] = red[0];
}

// ---------------- Adam ----------------
__global__ __launch_bounds__(256) void k_adam_f(float* __restrict__ p,
    float* __restrict__ m, float* __restrict__ v,
    const float* __restrict__ w, const float* __restrict__ X,
    const float* __restrict__ r, float bc1, float bc2)
{
  const int bid = blockIdx.x;
  const float rr = r[bid >> 3];
  const size_t base = (size_t)bid * 2048 + threadIdx.x * 4;
#pragma unroll
  for (int part = 0; part < 2; ++part) {
    const size_t off = base + part * 1024;
    float4 u  = *(const float4*)(X + off);
    const float4 u1 = *(const float4*)(X + (size_t)PN + off);
    u.x += u1.x; u.y += u1.y; u.z += u1.z; u.w += u1.w;
    const float4 w4 = *(const float4*)(w + off);
    const float wv[4] = {w4.x, w4.y, w4.z, w4.w};
    const float uu[4] = {u.x, u.y, u.z, u.w};
    float4 p4 = *(float4*)(p + off);
    float4 m4 = *(float4*)(m + off);
    float4 v4 = *(float4*)(v + off);
    float* pp = (float*)&p4; float* mm = (float*)&m4; float* vv = (float*)&v4;
#pragma unroll
    for (int e = 0; e < 4; ++e) {
      const float g  = wv[e] * (uu[e] - rr);
      const float mn = 0.9f*mm[e] + 0.1f*g;
      const float vn = 0.999f*vv[e] + 0.001f*(g*g);
      const float mh = mn / bc1, vh = vn / bc2;
      pp[e] = pp[e] - 1e-3f * mh / (sqrtf(vh) + 1e-8f);
      mm[e] = mn; vv[e] = vn;
    }
    *(float4*)(p + off) = p4;
    *(float4*)(m + off) = m4;
    *(float4*)(v + off) = v4;
  }
}

extern "C" void kernel_launch(void* const* d_in, const int* in_sizes, int n_in,
                              void* d_out, int out_size, void* d_ws, size_t ws_size,
                              hipStream_t stream) {
  const float* h = (const float*)d_in[0];
  const float* H = (const float*)d_in[1];
  (void)in_sizes; (void)n_in; (void)out_size; (void)ws_size;
  const int n_epoch = 1000;

  // floats: p,m,v (3PN) + w (PN) + X (2PN) + r (256)
  // ushorts: s-splits (3CN) + H-splits (3HN)
  // total 151,782,400 B (< proven-available ~156 MB: fast path ran R3-R5)
  float* p  = (float*)d_ws;
  float* m  = p + PN;
  float* v  = m + PN;
  float* w  = v + PN;
  float* X  = w + PN;                 // fwd: 32 slabs of CN ; bwd: 2 slabs of PN
  float* r  = X + (size_t)2*PN;       // 256
  ushort* s0 = (ushort*)(r + 256);
  ushort* s1 = s0 + CN, *s2 = s1 + CN;
  ushort* H0 = s2 + CN, *H1 = H0 + HN, *H2 = H1 + HN;

  hipMemsetAsync(p, 0, (size_t)3*PN*sizeof(float), stream);
  k_prep<<<HN/1024, 256, 0, stream>>>(H, H0, H1, H2);

  for (int s = 1; s <= n_epoch; ++s) {
    k_softmax_f<<<BB, 256, 0, stream>>>(p, w);
    k_fwd_v<<<dim3(16, FWD_SLABS), 256, 0, stream>>>(w, H, X);
    k_reduce_S2s<<<CN/1024, 256, 0, stream>>>(X, h, s0, s1, s2);
    k_gemm6_bwd<<<dim3(128, BWD_SLABS), 256, 0, stream>>>(s0, s1, s2, H0, H1, H2, X);
    k_rdot_f<<<BB, 256, 0, stream>>>(X, w, r);
    const float bc1 = 1.0f - powf(0.9f,   (float)s);
    const float bc2 = 1.0f - powf(0.999f, (float)s);
    k_adam_f<<<1024, 256, 0, stream>>>(p, m, v, w, X, r, bc1, bc2);
  }
  k_softmax_f<<<BB, 256, 0, stream>>>(p, (float*)d_out);
}

// Round 8
// 132253.613 us; speedup vs baseline: 2.4457x; 1.0829x over previous
//
#include <hip/hip_runtime.h>
#include <math.h>

#define BB 128
#define NTR 16384
#define DD 1024
#define PN (BB*NTR)     // 2097152
#define CN (BB*DD)      // 131072
#define HN (NTR*DD)     // 16777216
#define FWD_SLABS 32    // fwd split-K: 32 slabs of CN = 2*PN floats
#define BWD_SLABS 2     // bwd split-K: 2 slabs of PN

typedef short bf16x8 __attribute__((ext_vector_type(8)));
typedef float f32x2  __attribute__((ext_vector_type(2)));
typedef float f32x4v __attribute__((ext_vector_type(4)));

// ---------------- bf16 split helpers ----------------
__device__ __forceinline__ ushort f2bf(float f) {
  uint u = __float_as_uint(f);
  return (ushort)((u + 0x7FFFu + ((u >> 16) & 1u)) >> 16);   // RNE
}
__device__ __forceinline__ float bf2f(ushort h) { return __uint_as_float(((uint)h) << 16); }
__device__ __forceinline__ void split3(float f, ushort& a, ushort& b, ushort& c) {
  a = f2bf(f); float r1 = f - bf2f(a);
  b = f2bf(r1); float r2 = r1 - bf2f(b);
  c = f2bf(r2);
}
__device__ __forceinline__ void split2(float f, ushort& a, ushort& b) {
  a = f2bf(f); float r1 = f - bf2f(a);
  b = f2bf(r1);
}

// ---------------- one-time: split H (row-major) ----------------
__global__ __launch_bounds__(256) void k_prep(const float* __restrict__ H,
    ushort* __restrict__ H0, ushort* __restrict__ H1, ushort* __restrict__ H2)
{
  const size_t i = ((size_t)blockIdx.x * 256 + threadIdx.x) * 4;
  const float4 x = *(const float4*)(H + i);
  ushort a[4], b[4], c[4];
  split3(x.x, a[0], b[0], c[0]); split3(x.y, a[1], b[1], c[1]);
  split3(x.z, a[2], b[2], c[2]); split3(x.w, a[3], b[3], c[3]);
  *(ushort4*)(H0 + i) = make_ushort4(a[0], a[1], a[2], a[3]);
  *(ushort4*)(H1 + i) = make_ushort4(b[0], b[1], b[2], b[3]);
  *(ushort4*)(H2 + i) = make_ushort4(c[0], c[1], c[2], c[3]);
}

// ---------------- softmax: p -> w (fp32) ----------------
__global__ __launch_bounds__(256) void k_softmax_f(const float* __restrict__ p,
                                                   float* __restrict__ w) {
  const int row = blockIdx.x, tid = threadIdx.x;
  const float* pr = p + (size_t)row * NTR;
  float x[64]; float mx = -INFINITY;
#pragma unroll
  for (int i = 0; i < 64; ++i) { x[i] = pr[i*256 + tid]; mx = fmaxf(mx, x[i]); }
  __shared__ float red[256];
  red[tid] = mx; __syncthreads();
  for (int s = 128; s > 0; s >>= 1) { if (tid < s) red[tid] = fmaxf(red[tid], red[tid+s]); __syncthreads(); }
  mx = red[0]; __syncthreads();
  float sum = 0.f;
#pragma unroll
  for (int i = 0; i < 64; ++i) { x[i] = expf(x[i] - mx); sum += x[i]; }
  red[tid] = sum; __syncthreads();
  for (int s = 128; s > 0; s >>= 1) { if (tid < s) red[tid] += red[tid+s]; __syncthreads(); }
  const float inv = 1.0f / red[0];
  float* wr = w + (size_t)row * NTR;
#pragma unroll
  for (int i = 0; i < 64; ++i) wr[i*256 + tid] = x[i] * inv;
}

// ---------------- VALU fp32 forward (packed v_pk_fma_f32): C(slab) = w @ H ----------------
// grid (16 n-tiles of 64, 32 k-slabs), block 256, tile 128x64, micro 8x4.
// NOTE: per-output accumulation order identical to R6's scalar version -> bit-identical C.
__global__ __launch_bounds__(256) void k_fwd_v(const float* __restrict__ w,
    const float* __restrict__ H, float* __restrict__ Cp)
{
  const int nt = blockIdx.x, tid = threadIdx.x;
  const int kbase = blockIdx.y * 512;
  Cp += (size_t)blockIdx.y * CN;
  __shared__ float As[8][128];
  __shared__ float Bs[8][64];
  const int tm = tid >> 4, tn = tid & 15;
  const int m0 = tm * 8, n0 = tn * 4;
  f32x2 acc[8][2];
#pragma unroll
  for (int i = 0; i < 8; ++i) { acc[i][0] = (f32x2){0.f,0.f}; acc[i][1] = (f32x2){0.f,0.f}; }
  for (int kk = 0; kk < 512; kk += 8) {
    {
      const int mm = tid >> 1, q = tid & 1;
      const float4 a4 = *(const float4*)(w + (size_t)mm*NTR + kbase + kk + q*4);
      As[q*4+0][mm]=a4.x; As[q*4+1][mm]=a4.y; As[q*4+2][mm]=a4.z; As[q*4+3][mm]=a4.w;
    }
    if (tid < 128) {
      const int r = tid >> 4, c = (tid & 15) * 4;
      *(float4*)&Bs[r][c] = *(const float4*)(H + (size_t)(kbase+kk+r)*DD + nt*64 + c);
    }
    __syncthreads();
#pragma unroll
    for (int k = 0; k < 8; ++k) {
      float a[8];
      *(float4*)&a[0] = *(const float4*)&As[k][m0];
      *(float4*)&a[4] = *(const float4*)&As[k][m0+4];
      const f32x2 b0 = *(const f32x2*)&Bs[k][n0];
      const f32x2 b1 = *(const f32x2*)&Bs[k][n0+2];
#pragma unroll
      for (int i = 0; i < 8; ++i) {
        const f32x2 ai = (f32x2){a[i], a[i]};
        acc[i][0] = __builtin_elementwise_fma(ai, b0, acc[i][0]);
        acc[i][1] = __builtin_elementwise_fma(ai, b1, acc[i][1]);
      }
    }
    __syncthreads();
  }
#pragma unroll
  for (int i = 0; i < 8; ++i)
    *(float4*)(Cp + (size_t)(m0+i)*DD + nt*64 + n0) =
        make_float4(acc[i][0].x, acc[i][0].y, acc[i][1].x, acc[i][1].y);
}

// ---------------- S2 = 2*(sum_32 slabs - h), emit 2-way splits for bwd ----------------
__global__ __launch_bounds__(256) void k_reduce_S2s(const float* __restrict__ X,
    const float* __restrict__ h,
    ushort* __restrict__ s0, ushort* __restrict__ s1)
{
  const size_t off = ((size_t)blockIdx.x * 256 + threadIdx.x) * 4;
  float4 s = make_float4(0.f, 0.f, 0.f, 0.f);
#pragma unroll 4
  for (int k = 0; k < FWD_SLABS; ++k) {
    const float4 c = *(const float4*)(X + (size_t)k * CN + off);
    s.x += c.x; s.y += c.y; s.z += c.z; s.w += c.w;
  }
  const float4 hh = *(const float4*)(h + off);
  float vals[4] = {2.f*(s.x-hh.x), 2.f*(s.y-hh.y), 2.f*(s.z-hh.z), 2.f*(s.w-hh.w)};
  ushort a[4], b[4];
#pragma unroll
  for (int e = 0; e < 4; ++e) split2(vals[e], a[e], b[e]);
  *(ushort4*)(s0 + off) = make_ushort4(a[0], a[1], a[2], a[3]);
  *(ushort4*)(s1 + off) = make_ushort4(b[0], b[1], b[2], b[3]);
}

// ---------------- BACKWARD 3-product MFMA GEMM: dw(slab) = S2[128 x 512k] @ H^T ----------------
// 2-split A (S2) x 2-split B (H), products {aa', ab', ba'} — bwd numerics proven
// output-insensitive down to the 6-product class (R3==R5); one class lower here.
__global__ __launch_bounds__(256, 2) void k_gemm3_bwd(
    const ushort* __restrict__ A0, const ushort* __restrict__ A1,
    const ushort* __restrict__ B0, const ushort* __restrict__ B1,
    float* __restrict__ C)
{
  __shared__ ushort lds[16384];   // A: 2*[128][32] = 8192 ; B: 2*[128][32] = 8192
  const int tid = threadIdx.x;
  const int lane = tid & 63, wid = tid >> 6;
  const int wm = (wid >> 1) * 64, wn = (wid & 1) * 64;
  const int n0 = blockIdx.x * 128;
  const int kbase = blockIdx.y * 512;
  C += (size_t)blockIdx.y * PN;

  const ushort* Ap[2] = {A0, A1};
  const ushort* Bp[2] = {B0, B1};

  f32x4v acc[4][4];
#pragma unroll
  for (int i = 0; i < 4; ++i)
#pragma unroll
    for (int j = 0; j < 4; ++j) acc[i][j] = (f32x4v){0.f, 0.f, 0.f, 0.f};

  for (int kt = 0; kt < 16; ++kt) {
    const int kpos = kbase + (kt << 5);
#pragma unroll
    for (int c = 0; c < 4; ++c) {
      const int L = c*256 + tid;
      const int s = L >> 9, rr = L & 511;
      const int row = rr >> 2, slot = rr & 3;
      const int sl = slot ^ ((row >> 1) & 3);
      const ushort* src = Ap[s] + (size_t)row * DD + kpos + (sl << 3);
      __builtin_amdgcn_global_load_lds((const __attribute__((address_space(1))) void*)src,
          (__attribute__((address_space(3))) void*)&lds[(size_t)(c*256 + (wid << 6)) * 8], 16, 0, 0);
    }
#pragma unroll
    for (int c = 0; c < 4; ++c) {
      const int L = c*256 + tid;
      const int s = L >> 9, rr = L & 511;
      const int row = rr >> 2, slot = rr & 3;
      const int sl = slot ^ ((row >> 1) & 3);
      const ushort* src = Bp[s] + (size_t)(n0 + row) * DD + kpos + (sl << 3);
      __builtin_amdgcn_global_load_lds((const __attribute__((address_space(1))) void*)src,
          (__attribute__((address_space(3))) void*)&lds[8192 + (size_t)(c*256 + (wid << 6)) * 8], 16, 0, 0);
    }
    __syncthreads();

    bf16x8 bf[2][4];
#pragma unroll
    for (int s = 0; s < 2; ++s)
#pragma unroll
      for (int j = 0; j < 4; ++j) {
        const int n = wn + j*16 + (lane & 15);
        const int sl = (lane >> 4) ^ ((n >> 1) & 3);
        bf[s][j] = *(const bf16x8*)&lds[8192 + s*4096 + n*32 + sl*8];
      }
#pragma unroll
    for (int sa = 0; sa < 2; ++sa) {
      bf16x8 af[4];
#pragma unroll
      for (int i = 0; i < 4; ++i) {
        const int mrow = wm + i*16 + (lane & 15);
        const int sl = (lane >> 4) ^ ((mrow >> 1) & 3);
        af[i] = *(const bf16x8*)&lds[sa*4096 + mrow*32 + sl*8];
      }
#pragma unroll
      for (int sb = 0; sb < 2 - sa; ++sb)
#pragma unroll
        for (int i = 0; i < 4; ++i)
#pragma unroll
          for (int j = 0; j < 4; ++j)
            acc[i][j] = __builtin_amdgcn_mfma_f32_16x16x32_bf16(af[i], bf[sb][j], acc[i][j], 0, 0, 0);
    }
    __syncthreads();
  }
#pragma unroll
  for (int i = 0; i < 4; ++i) {
    const int rbase = wm + i*16 + ((lane >> 4) << 2);
#pragma unroll
    for (int j = 0; j < 4; ++j) {
      const int cg = n0 + wn + j*16 + (lane & 15);
#pragma unroll
      for (int r = 0; r < 4; ++r)
        C[(size_t)(rbase + r) * NTR + cg] = acc[i][j][r];
    }
  }
}

// ---------------- r[row] = sum_j w[row][j] * u[row][j] (u = 2 dw slabs) ----------------
__global__ __launch_bounds__(256) void k_rdot_f(const float* __restrict__ X,
    const float* __restrict__ w, float* __restrict__ r)
{
  const int row = blockIdx.x, tid = threadIdx.x;
  const size_t rb = (size_t)row * NTR;
  float sum = 0.f;
  for (int c = 0; c < 16; ++c) {
    const size_t off = rb + (size_t)c * 1024 + tid * 4;
    float4 u  = *(const float4*)(X + off);
    const float4 u1 = *(const float4*)(X + (size_t)PN + off);
    u.x += u1.x; u.y += u1.y; u.z += u1.z; u.w += u1.w;
    const float4 ww = *(const float4*)(w + off);
    sum += ww.x*u.x + ww.y*u.y + ww.z*u.z + ww.w*u.w;
  }
  __shared__ float red[256];
  red[tid] = sum; __syncthreads();
  for (int s = 128; s > 0; s >>= 1) { if (tid < s) red[tid] += red[tid+s]; __syncthreads(); }
  if (tid == 0) r[row] = red[0];
}

// ---------------- Adam ----------------
__global__ __launch_bounds__(256) void k_adam_f(float* __restrict__ p,
    float* __restrict__ m, float* __restrict__ v,
    const float* __restrict__ w, const float* __restrict__ X,
    const float* __restrict__ r, float bc1, float bc2)
{
  const int bid = blockIdx.x;
  const float rr = r[bid >> 3];
  const size_t base = (size_t)bid * 2048 + threadIdx.x * 4;
#pragma unroll
  for (int part = 0; part < 2; ++part) {
    const size_t off = base + part * 1024;
    float4 u  = *(const float4*)(X + off);
    const float4 u1 = *(const float4*)(X + (size_t)PN + off);
    u.x += u1.x; u.y += u1.y; u.z += u1.z; u.w += u1.w;
    const float4 w4 = *(const float4*)(w + off);
    const float wv[4] = {w4.x, w4.y, w4.z, w4.w};
    const float uu[4] = {u.x, u.y, u.z, u.w};
    float4 p4 = *(float4*)(p + off);
    float4 m4 = *(float4*)(m + off);
    float4 v4 = *(float4*)(v + off);
    float* pp = (float*)&p4; float* mm = (float*)&m4; float* vv = (float*)&v4;
#pragma unroll
    for (int e = 0; e < 4; ++e) {
      const float g  = wv[e] * (uu[e] - rr);
      const float mn = 0.9f*mm[e] + 0.1f*g;
      const float vn = 0.999f*vv[e] + 0.001f*(g*g);
      const float mh = mn / bc1, vh = vn / bc2;
      pp[e] = pp[e] - 1e-3f * mh / (sqrtf(vh) + 1e-8f);
      mm[e] = mn; vv[e] = vn;
    }
    *(float4*)(p + off) = p4;
    *(float4*)(m + off) = m4;
    *(float4*)(v + off) = v4;
  }
}

extern "C" void kernel_launch(void* const* d_in, const int* in_sizes, int n_in,
                              void* d_out, int out_size, void* d_ws, size_t ws_size,
                              hipStream_t stream) {
  const float* h = (const float*)d_in[0];
  const float* H = (const float*)d_in[1];
  (void)in_sizes; (void)n_in; (void)out_size; (void)ws_size;
  const int n_epoch = 1000;

  // R6-proven layout (151,782,400 B):
  // floats: p,m,v (3PN) + w (PN) + X (2PN) + r (256)
  // ushorts: s-splits (3CN; s2 slot reserved/unused) + H-splits (3HN; H2 used by prep only)
  float* p  = (float*)d_ws;
  float* m  = p + PN;
  float* v  = m + PN;
  float* w  = v + PN;
  float* X  = w + PN;                 // fwd: 32 slabs of CN ; bwd: 2 slabs of PN
  float* r  = X + (size_t)2*PN;       // 256
  ushort* s0 = (ushort*)(r + 256);
  ushort* s1 = s0 + CN, *s2 = s1 + CN;
  ushort* H0 = s2 + CN, *H1 = H0 + HN, *H2 = H1 + HN;
  (void)s2;

  hipMemsetAsync(p, 0, (size_t)3*PN*sizeof(float), stream);
  k_prep<<<HN/1024, 256, 0, stream>>>(H, H0, H1, H2);

  for (int s = 1; s <= n_epoch; ++s) {
    k_softmax_f<<<BB, 256, 0, stream>>>(p, w);
    k_fwd_v<<<dim3(16, FWD_SLABS), 256, 0, stream>>>(w, H, X);
    k_reduce_S2s<<<CN/1024, 256, 0, stream>>>(X, h, s0, s1);
    k_gemm3_bwd<<<dim3(128, BWD_SLABS), 256, 0, stream>>>(s0, s1, H0, H1, X);
    k_rdot_f<<<BB, 256, 0, stream>>>(X, w, r);
    const float bc1 = 1.0f - powf(0.9f,   (float)s);
    const float bc2 = 1.0f - powf(0.999f, (float)s);
    k_adam_f<<<1024, 256, 0, stream>>>(p, m, v, w, X, r, bc1, bc2);
  }
  k_softmax_f<<<BB, 256, 0, stream>>>(p, (float*)d_out);
}

// Round 9
// 117033.044 us; speedup vs baseline: 2.7638x; 1.1301x over previous
//
#include <hip/hip_runtime.h>
#include <math.h>

#define BB 128
#define NTR 16384
#define DD 1024
#define PN (BB*NTR)     // 2097152
#define CN (BB*DD)      // 131072
#define HN (NTR*DD)     // 16777216
#define FWD_SLABS 64    // fwd split-K: 64 slabs of CN = 4*PN floats (k-chunk 256)
#define BWD_SLABS 2     // bwd split-K: 2 slabs of PN

typedef short bf16x8 __attribute__((ext_vector_type(8)));
typedef float f32x2  __attribute__((ext_vector_type(2)));
typedef float f32x4v __attribute__((ext_vector_type(4)));

// ---------------- bf16 split helpers ----------------
__device__ __forceinline__ ushort f2bf(float f) {
  uint u = __float_as_uint(f);
  return (ushort)((u + 0x7FFFu + ((u >> 16) & 1u)) >> 16);   // RNE
}
__device__ __forceinline__ float bf2f(ushort h) { return __uint_as_float(((uint)h) << 16); }
__device__ __forceinline__ void split2(float f, ushort& a, ushort& b) {
  a = f2bf(f); float r1 = f - bf2f(a);
  b = f2bf(r1);
}

// ---------------- one-time: 2-way split H (row-major) ----------------
__global__ __launch_bounds__(256) void k_prep(const float* __restrict__ H,
    ushort* __restrict__ H0, ushort* __restrict__ H1)
{
  const size_t i = ((size_t)blockIdx.x * 256 + threadIdx.x) * 4;
  const float4 x = *(const float4*)(H + i);
  ushort a[4], b[4];
  split2(x.x, a[0], b[0]); split2(x.y, a[1], b[1]);
  split2(x.z, a[2], b[2]); split2(x.w, a[3], b[3]);
  *(ushort4*)(H0 + i) = make_ushort4(a[0], a[1], a[2], a[3]);
  *(ushort4*)(H1 + i) = make_ushort4(b[0], b[1], b[2], b[3]);
}

// ---------------- softmax: p -> w (fp32) ----------------
__global__ __launch_bounds__(256) void k_softmax_f(const float* __restrict__ p,
                                                   float* __restrict__ w) {
  const int row = blockIdx.x, tid = threadIdx.x;
  const float* pr = p + (size_t)row * NTR;
  float x[64]; float mx = -INFINITY;
#pragma unroll
  for (int i = 0; i < 64; ++i) { x[i] = pr[i*256 + tid]; mx = fmaxf(mx, x[i]); }
  __shared__ float red[256];
  red[tid] = mx; __syncthreads();
  for (int s = 128; s > 0; s >>= 1) { if (tid < s) red[tid] = fmaxf(red[tid], red[tid+s]); __syncthreads(); }
  mx = red[0]; __syncthreads();
  float sum = 0.f;
#pragma unroll
  for (int i = 0; i < 64; ++i) { x[i] = expf(x[i] - mx); sum += x[i]; }
  red[tid] = sum; __syncthreads();
  for (int s = 128; s > 0; s >>= 1) { if (tid < s) red[tid] += red[tid+s]; __syncthreads(); }
  const float inv = 1.0f / red[0];
  float* wr = w + (size_t)row * NTR;
#pragma unroll
  for (int i = 0; i < 64; ++i) wr[i*256 + tid] = x[i] * inv;
}

// ---------------- VALU fp32 forward: C(slab) = w[128 x 256k] @ H[256k x 1024] ----------------
// grid (8 n-tiles of 128, 64 k-slabs) = 512 blocks (2/CU), block 256, micro 8x8 (VALU-bound).
// Per-output k-order sequential -> same rounding class as R6/R8.
__global__ __launch_bounds__(256) void k_fwd_v(const float* __restrict__ w,
    const float* __restrict__ H, float* __restrict__ Cp)
{
  const int nt = blockIdx.x, tid = threadIdx.x;
  const int kbase = blockIdx.y * 256;
  Cp += (size_t)blockIdx.y * CN;
  __shared__ float As[8][128];
  __shared__ float Bs[8][128];
  const int tm = tid >> 4, tn = tid & 15;
  const int m0 = tm * 8, n0 = tn * 8;
  f32x2 acc[8][4];
#pragma unroll
  for (int i = 0; i < 8; ++i)
#pragma unroll
    for (int j = 0; j < 4; ++j) acc[i][j] = (f32x2){0.f, 0.f};
  for (int kk = 0; kk < 256; kk += 8) {
    {
      const int mm = tid >> 1, q = tid & 1;
      const float4 a4 = *(const float4*)(w + (size_t)mm*NTR + kbase + kk + q*4);
      As[q*4+0][mm]=a4.x; As[q*4+1][mm]=a4.y; As[q*4+2][mm]=a4.z; As[q*4+3][mm]=a4.w;
    }
    {
      const int r = tid >> 5, c = (tid & 31) * 4;
      *(float4*)&Bs[r][c] = *(const float4*)(H + (size_t)(kbase+kk+r)*DD + nt*128 + c);
    }
    __syncthreads();
#pragma unroll
    for (int k = 0; k < 8; ++k) {
      float a[8];
      *(float4*)&a[0] = *(const float4*)&As[k][m0];
      *(float4*)&a[4] = *(const float4*)&As[k][m0+4];
      f32x2 b[4];
      b[0] = *(const f32x2*)&Bs[k][n0];
      b[1] = *(const f32x2*)&Bs[k][n0+2];
      b[2] = *(const f32x2*)&Bs[k][n0+4];
      b[3] = *(const f32x2*)&Bs[k][n0+6];
#pragma unroll
      for (int i = 0; i < 8; ++i) {
        const f32x2 ai = (f32x2){a[i], a[i]};
#pragma unroll
        for (int j = 0; j < 4; ++j)
          acc[i][j] = __builtin_elementwise_fma(ai, b[j], acc[i][j]);
      }
    }
    __syncthreads();
  }
#pragma unroll
  for (int i = 0; i < 8; ++i) {
    float* dst = Cp + (size_t)(m0+i)*DD + nt*128 + n0;
    *(float4*)dst     = make_float4(acc[i][0].x, acc[i][0].y, acc[i][1].x, acc[i][1].y);
    *(float4*)(dst+4) = make_float4(acc[i][2].x, acc[i][2].y, acc[i][3].x, acc[i][3].y);
  }
}

// ---------------- S2 = 2*(sum_64 slabs - h), emit 2-way splits for bwd ----------------
__global__ __launch_bounds__(256) void k_reduce_S2s(const float* __restrict__ X,
    const float* __restrict__ h,
    ushort* __restrict__ s0, ushort* __restrict__ s1)
{
  const size_t off = ((size_t)blockIdx.x * 256 + threadIdx.x) * 4;
  float4 s = make_float4(0.f, 0.f, 0.f, 0.f);
#pragma unroll 4
  for (int k = 0; k < FWD_SLABS; ++k) {
    const float4 c = *(const float4*)(X + (size_t)k * CN + off);
    s.x += c.x; s.y += c.y; s.z += c.z; s.w += c.w;
  }
  const float4 hh = *(const float4*)(h + off);
  float vals[4] = {2.f*(s.x-hh.x), 2.f*(s.y-hh.y), 2.f*(s.z-hh.z), 2.f*(s.w-hh.w)};
  ushort a[4], b[4];
#pragma unroll
  for (int e = 0; e < 4; ++e) split2(vals[e], a[e], b[e]);
  *(ushort4*)(s0 + off) = make_ushort4(a[0], a[1], a[2], a[3]);
  *(ushort4*)(s1 + off) = make_ushort4(b[0], b[1], b[2], b[3]);
}

// ---------------- BACKWARD 3-product MFMA GEMM + fused rpart epilogue ----------------
// dw(slab) = S2[128 x 512k] @ H^T ; rpart[(ks*128+bn)*128+row] = sum_cols w*dwpart
__global__ __launch_bounds__(256, 2) void k_gemm3_bwd(
    const ushort* __restrict__ A0, const ushort* __restrict__ A1,
    const ushort* __restrict__ B0, const ushort* __restrict__ B1,
    const float* __restrict__ w,
    float* __restrict__ C, float* __restrict__ rpart)
{
  __shared__ ushort lds[16384];   // A: 2*[128][32] ; B: 2*[128][32]
  __shared__ float rbuf[128][33];
  const int tid = threadIdx.x;
  const int lane = tid & 63, wid = tid >> 6;
  const int wm = (wid >> 1) * 64, wn = (wid & 1) * 64;
  const int bn = blockIdx.x, ks = blockIdx.y;
  const int n0 = bn * 128;
  const int kbase = ks * 512;
  C += (size_t)ks * PN;

  const ushort* Ap[2] = {A0, A1};
  const ushort* Bp[2] = {B0, B1};

  f32x4v acc[4][4];
#pragma unroll
  for (int i = 0; i < 4; ++i)
#pragma unroll
    for (int j = 0; j < 4; ++j) acc[i][j] = (f32x4v){0.f, 0.f, 0.f, 0.f};

  for (int kt = 0; kt < 16; ++kt) {
    const int kpos = kbase + (kt << 5);
#pragma unroll
    for (int c = 0; c < 4; ++c) {
      const int L = c*256 + tid;
      const int s = L >> 9, rr = L & 511;
      const int row = rr >> 2, slot = rr & 3;
      const int sl = slot ^ ((row >> 1) & 3);
      const ushort* src = Ap[s] + (size_t)row * DD + kpos + (sl << 3);
      __builtin_amdgcn_global_load_lds((const __attribute__((address_space(1))) void*)src,
          (__attribute__((address_space(3))) void*)&lds[(size_t)(c*256 + (wid << 6)) * 8], 16, 0, 0);
    }
#pragma unroll
    for (int c = 0; c < 4; ++c) {
      const int L = c*256 + tid;
      const int s = L >> 9, rr = L & 511;
      const int row = rr >> 2, slot = rr & 3;
      const int sl = slot ^ ((row >> 1) & 3);
      const ushort* src = Bp[s] + (size_t)(n0 + row) * DD + kpos + (sl << 3);
      __builtin_amdgcn_global_load_lds((const __attribute__((address_space(1))) void*)src,
          (__attribute__((address_space(3))) void*)&lds[8192 + (size_t)(c*256 + (wid << 6)) * 8], 16, 0, 0);
    }
    __syncthreads();

    bf16x8 bf[2][4];
#pragma unroll
    for (int s = 0; s < 2; ++s)
#pragma unroll
      for (int j = 0; j < 4; ++j) {
        const int n = wn + j*16 + (lane & 15);
        const int sl = (lane >> 4) ^ ((n >> 1) & 3);
        bf[s][j] = *(const bf16x8*)&lds[8192 + s*4096 + n*32 + sl*8];
      }
#pragma unroll
    for (int sa = 0; sa < 2; ++sa) {
      bf16x8 af[4];
#pragma unroll
      for (int i = 0; i < 4; ++i) {
        const int mrow = wm + i*16 + (lane & 15);
        const int sl = (lane >> 4) ^ ((mrow >> 1) & 3);
        af[i] = *(const bf16x8*)&lds[sa*4096 + mrow*32 + sl*8];
      }
#pragma unroll
      for (int sb = 0; sb < 2 - sa; ++sb)
#pragma unroll
        for (int i = 0; i < 4; ++i)
#pragma unroll
          for (int j = 0; j < 4; ++j)
            acc[i][j] = __builtin_amdgcn_mfma_f32_16x16x32_bf16(af[i], bf[sb][j], acc[i][j], 0, 0, 0);
    }
    __syncthreads();
  }
  // epilogue: store dw slab + fused w-weighted row partials
#pragma unroll
  for (int i = 0; i < 4; ++i) {
    const int rbase = wm + i*16 + ((lane >> 4) << 2);
#pragma unroll
    for (int r = 0; r < 4; ++r) {
      const int row = rbase + r;
      float s = 0.f;
#pragma unroll
      for (int j = 0; j < 4; ++j) {
        const int cg = n0 + wn + j*16 + (lane & 15);
        C[(size_t)row * NTR + cg] = acc[i][j][r];
        s = fmaf(w[(size_t)row * NTR + cg], acc[i][j][r], s);
      }
      rbuf[row][((wid & 1) << 4) + (lane & 15)] = s;
    }
  }
  __syncthreads();
  if (tid < 128) {
    float s = 0.f;
#pragma unroll
    for (int t = 0; t < 32; ++t) s += rbuf[tid][t];
    rpart[((size_t)ks*128 + bn)*128 + tid] = s;
  }
}

// ---------------- Adam (reduces rpart; u = 2 dw slabs) ----------------
__global__ __launch_bounds__(256) void k_adam_f(float* __restrict__ p,
    float* __restrict__ m, float* __restrict__ v,
    const float* __restrict__ w, const float* __restrict__ X,
    const float* __restrict__ rpart, float bc1, float bc2)
{
  const int bid = blockIdx.x, tid = threadIdx.x;
  const int row = bid >> 3;
  __shared__ float red[256];
  red[tid] = rpart[(size_t)tid*128 + row];
  __syncthreads();
  for (int s = 128; s > 0; s >>= 1) { if (tid < s) red[tid] += red[tid+s]; __syncthreads(); }
  const float rr = red[0];
  const size_t base = (size_t)bid * 2048 + tid * 4;
#pragma unroll
  for (int part = 0; part < 2; ++part) {
    const size_t off = base + part * 1024;
    float4 u  = *(const float4*)(X + off);
    const float4 u1 = *(const float4*)(X + (size_t)PN + off);
    u.x += u1.x; u.y += u1.y; u.z += u1.z; u.w += u1.w;
    const float4 w4 = *(const float4*)(w + off);
    const float wv[4] = {w4.x, w4.y, w4.z, w4.w};
    const float uu[4] = {u.x, u.y, u.z, u.w};
    float4 p4 = *(float4*)(p + off);
    float4 m4 = *(float4*)(m + off);
    float4 v4 = *(float4*)(v + off);
    float* pp = (float*)&p4; float* mm = (float*)&m4; float* vv = (float*)&v4;
#pragma unroll
    for (int e = 0; e < 4; ++e) {
      const float g  = wv[e] * (uu[e] - rr);
      const float mn = 0.9f*mm[e] + 0.1f*g;
      const float vn = 0.999f*vv[e] + 0.001f*(g*g);
      const float mh = mn / bc1, vh = vn / bc2;
      pp[e] = pp[e] - 1e-3f * mh / (sqrtf(vh) + 1e-8f);
      mm[e] = mn; vv[e] = vn;
    }
    *(float4*)(p + off) = p4;
    *(float4*)(m + off) = m4;
    *(float4*)(v + off) = v4;
  }
}

extern "C" void kernel_launch(void* const* d_in, const int* in_sizes, int n_in,
                              void* d_out, int out_size, void* d_ws, size_t ws_size,
                              hipStream_t stream) {
  const float* h = (const float*)d_in[0];
  const float* H = (const float*)d_in[1];
  (void)in_sizes; (void)n_in; (void)out_size; (void)ws_size;
  const int n_epoch = 1000;

  // floats: p,m,v (3PN) + w (PN) + X (4PN: fwd 64 slabs of CN / bwd 2 slabs of PN) + rpart (32768)
  // ushorts: s-splits (2CN) + H-splits (2HN)   -> ~134.9 MB total (fits; >=156 MB proven available)
  float* p  = (float*)d_ws;
  float* m  = p + PN;
  float* v  = m + PN;
  float* w  = v + PN;
  float* X  = w + PN;
  float* rp = X + (size_t)4*PN;        // 256*128
  ushort* s0 = (ushort*)(rp + 256*128);
  ushort* s1 = s0 + CN;
  ushort* H0 = s1 + CN, *H1 = H0 + HN;

  hipMemsetAsync(p, 0, (size_t)3*PN*sizeof(float), stream);
  k_prep<<<HN/1024, 256, 0, stream>>>(H, H0, H1);

  for (int s = 1; s <= n_epoch; ++s) {
    k_softmax_f<<<BB, 256, 0, stream>>>(p, w);
    k_fwd_v<<<dim3(8, FWD_SLABS), 256, 0, stream>>>(w, H, X);
    k_reduce_S2s<<<CN/1024, 256, 0, stream>>>(X, h, s0, s1);
    k_gemm3_bwd<<<dim3(128, BWD_SLABS), 256, 0, stream>>>(s0, s1, H0, H1, w, X, rp);
    const float bc1 = 1.0f - powf(0.9f,   (float)s);
    const float bc2 = 1.0f - powf(0.999f, (float)s);
    k_adam_f<<<1024, 256, 0, stream>>>(p, m, v, w, X, rp, bc1, bc2);
  }
  k_softmax_f<<<BB, 256, 0, stream>>>(p, (float*)d_out);
}

// Round 10
// 109975.049 us; speedup vs baseline: 2.9412x; 1.0642x over previous
//
#include <hip/hip_runtime.h>
#include <math.h>

#define BB 128
#define NTR 16384
#define DD 1024
#define PN (BB*NTR)     // 2097152
#define CN (BB*DD)      // 131072
#define HN (NTR*DD)     // 16777216
#define FWD_SLABS 64    // fwd split-K: 64 slabs of CN = 4*PN floats (k-chunk 256)
#define BWD_SLABS 2     // bwd split-K: 2 slabs of PN (k-chunk 512)

typedef short bf16x8 __attribute__((ext_vector_type(8)));
typedef float f32x2  __attribute__((ext_vector_type(2)));
typedef float f32x4v __attribute__((ext_vector_type(4)));

// ---------------- bf16 split helpers ----------------
__device__ __forceinline__ ushort f2bf(float f) {
  uint u = __float_as_uint(f);
  return (ushort)((u + 0x7FFFu + ((u >> 16) & 1u)) >> 16);   // RNE
}
__device__ __forceinline__ float bf2f(ushort h) { return __uint_as_float(((uint)h) << 16); }
__device__ __forceinline__ void split2(float f, ushort& a, ushort& b) {
  a = f2bf(f); float r1 = f - bf2f(a);
  b = f2bf(r1);
}

// ---------------- one-time: 2-way split H (row-major) ----------------
__global__ __launch_bounds__(256) void k_prep(const float* __restrict__ H,
    ushort* __restrict__ H0, ushort* __restrict__ H1)
{
  const size_t i = ((size_t)blockIdx.x * 256 + threadIdx.x) * 4;
  const float4 x = *(const float4*)(H + i);
  ushort a[4], b[4];
  split2(x.x, a[0], b[0]); split2(x.y, a[1], b[1]);
  split2(x.z, a[2], b[2]); split2(x.w, a[3], b[3]);
  *(ushort4*)(H0 + i) = make_ushort4(a[0], a[1], a[2], a[3]);
  *(ushort4*)(H1 + i) = make_ushort4(b[0], b[1], b[2], b[3]);
}

// ---------------- softmax: p -> w (fp32), 512 threads/row ----------------
__global__ __launch_bounds__(512) void k_softmax_f(const float* __restrict__ p,
                                                   float* __restrict__ w) {
  const int row = blockIdx.x, tid = threadIdx.x;
  const float* pr = p + (size_t)row * NTR;
  float x[32]; float mx = -INFINITY;
#pragma unroll
  for (int i = 0; i < 32; ++i) { x[i] = pr[i*512 + tid]; mx = fmaxf(mx, x[i]); }
  __shared__ float red[512];
  red[tid] = mx; __syncthreads();
  for (int s = 256; s > 0; s >>= 1) { if (tid < s) red[tid] = fmaxf(red[tid], red[tid+s]); __syncthreads(); }
  mx = red[0]; __syncthreads();
  float sum = 0.f;
#pragma unroll
  for (int i = 0; i < 32; ++i) { x[i] = expf(x[i] - mx); sum += x[i]; }
  red[tid] = sum; __syncthreads();
  for (int s = 256; s > 0; s >>= 1) { if (tid < s) red[tid] += red[tid+s]; __syncthreads(); }
  const float inv = 1.0f / red[0];
  float* wr = w + (size_t)row * NTR;
#pragma unroll
  for (int i = 0; i < 32; ++i) wr[i*512 + tid] = x[i] * inv;
}

// ---------------- VALU fp32 forward w/ register-prefetch: C(slab) = w @ H ----------------
// grid (8 n-tiles of 128, 64 k-slabs) = 512 blocks (2/CU), block 256, micro 8x8.
// LDS content per k-step identical to R9 -> bit-identical C.
__global__ __launch_bounds__(256) void k_fwd_v(const float* __restrict__ w,
    const float* __restrict__ H, float* __restrict__ Cp)
{
  const int nt = blockIdx.x, tid = threadIdx.x;
  const int kbase = blockIdx.y * 256;
  Cp += (size_t)blockIdx.y * CN;
  __shared__ float As[8][128];
  __shared__ float Bs[8][128];
  const int tm = tid >> 4, tn = tid & 15;
  const int m0 = tm * 8, n0 = tn * 8;
  const int mm = tid >> 1, q = tid & 1;        // A-staging coords
  const int br = tid >> 5, bc = (tid & 31) * 4; // B-staging coords
  const float* Asrc = w + (size_t)mm*NTR + kbase + q*4;
  const float* Bsrc = H + (size_t)(kbase+br)*DD + nt*128 + bc;

  f32x2 acc[8][4];
#pragma unroll
  for (int i = 0; i < 8; ++i)
#pragma unroll
    for (int j = 0; j < 4; ++j) acc[i][j] = (f32x2){0.f, 0.f};

  float4 ra = *(const float4*)(Asrc);
  float4 rb = *(const float4*)(Bsrc);
  for (int kk = 0; kk < 256; kk += 8) {
    __syncthreads();
    As[q*4+0][mm]=ra.x; As[q*4+1][mm]=ra.y; As[q*4+2][mm]=ra.z; As[q*4+3][mm]=ra.w;
    *(float4*)&Bs[br][bc] = rb;
    __syncthreads();
    if (kk + 8 < 256) {                         // prefetch next k-step; hides under compute
      ra = *(const float4*)(Asrc + kk + 8);
      rb = *(const float4*)(Bsrc + (size_t)(kk+8)*DD);
    }
#pragma unroll
    for (int k = 0; k < 8; ++k) {
      float a[8];
      *(float4*)&a[0] = *(const float4*)&As[k][m0];
      *(float4*)&a[4] = *(const float4*)&As[k][m0+4];
      f32x2 b[4];
      b[0] = *(const f32x2*)&Bs[k][n0];
      b[1] = *(const f32x2*)&Bs[k][n0+2];
      b[2] = *(const f32x2*)&Bs[k][n0+4];
      b[3] = *(const f32x2*)&Bs[k][n0+6];
#pragma unroll
      for (int i = 0; i < 8; ++i) {
        const f32x2 ai = (f32x2){a[i], a[i]};
#pragma unroll
        for (int j = 0; j < 4; ++j)
          acc[i][j] = __builtin_elementwise_fma(ai, b[j], acc[i][j]);
      }
    }
  }
#pragma unroll
  for (int i = 0; i < 8; ++i) {
    float* dst = Cp + (size_t)(m0+i)*DD + nt*128 + n0;
    *(float4*)dst     = make_float4(acc[i][0].x, acc[i][0].y, acc[i][1].x, acc[i][1].y);
    *(float4*)(dst+4) = make_float4(acc[i][2].x, acc[i][2].y, acc[i][3].x, acc[i][3].y);
  }
}

// ---------------- S2 = 2*(sum_64 slabs - h), emit 2-way splits (256 blocks) ----------------
__global__ __launch_bounds__(256) void k_reduce_S2s(const float* __restrict__ X,
    const float* __restrict__ h,
    ushort* __restrict__ s0, ushort* __restrict__ s1)
{
  const size_t off = ((size_t)blockIdx.x * 256 + threadIdx.x) * 2;
  f32x2 s = (f32x2){0.f, 0.f};
#pragma unroll 4
  for (int k = 0; k < FWD_SLABS; ++k) {
    const f32x2 c = *(const f32x2*)(X + (size_t)k * CN + off);
    s.x += c.x; s.y += c.y;
  }
  const f32x2 hh = *(const f32x2*)(h + off);
  float v0 = 2.f*(s.x-hh.x), v1 = 2.f*(s.y-hh.y);
  ushort a0, b0, a1, b1;
  split2(v0, a0, b0); split2(v1, a1, b1);
  *(ushort2*)(s0 + off) = make_ushort2(a0, a1);
  *(ushort2*)(s1 + off) = make_ushort2(b0, b1);
}

// ---------------- BACKWARD 3-product MFMA GEMM, 64-col tiles (512 blocks) ----------------
// dw(slab) = S2[128 x 1024-k] @ H^T ; fused w-weighted row partials
__global__ __launch_bounds__(256, 2) void k_gemm3_bwd(
    const ushort* __restrict__ A0, const ushort* __restrict__ A1,
    const ushort* __restrict__ B0, const ushort* __restrict__ B1,
    const float* __restrict__ w,
    float* __restrict__ C, float* __restrict__ rpart)
{
  __shared__ ushort lds[12288];   // A: 2*[128][32] = 8192 ; B: 2*[64][32] = 4096
  __shared__ float rbuf[128][33];
  const int tid = threadIdx.x;
  const int lane = tid & 63, wid = tid >> 6;
  const int wm = (wid >> 1) * 64, wn = (wid & 1) * 32;
  const int bn = blockIdx.x, ks = blockIdx.y;
  const int n0 = bn * 64;
  const int kbase = ks * 512;
  C += (size_t)ks * PN;

  const ushort* Ap[2] = {A0, A1};
  const ushort* Bp[2] = {B0, B1};

  f32x4v acc[4][2];
#pragma unroll
  for (int i = 0; i < 4; ++i)
#pragma unroll
    for (int j = 0; j < 2; ++j) acc[i][j] = (f32x4v){0.f, 0.f, 0.f, 0.f};

  for (int kt = 0; kt < 16; ++kt) {
    const int kpos = kbase + (kt << 5);
#pragma unroll
    for (int c = 0; c < 4; ++c) {      // A: 1024 chunks
      const int L = c*256 + tid;
      const int s = L >> 9, rr = L & 511;
      const int row = rr >> 2, slot = rr & 3;
      const int sl = slot ^ ((row >> 1) & 3);
      const ushort* src = Ap[s] + (size_t)row * DD + kpos + (sl << 3);
      __builtin_amdgcn_global_load_lds((const __attribute__((address_space(1))) void*)src,
          (__attribute__((address_space(3))) void*)&lds[(size_t)(c*256 + (wid << 6)) * 8], 16, 0, 0);
    }
#pragma unroll
    for (int c = 0; c < 2; ++c) {      // B: 512 chunks
      const int L = c*256 + tid;
      const int s = L >> 8, rr = L & 255;
      const int row = rr >> 2, slot = rr & 3;
      const int sl = slot ^ ((row >> 1) & 3);
      const ushort* src = Bp[s] + (size_t)(n0 + row) * DD + kpos + (sl << 3);
      __builtin_amdgcn_global_load_lds((const __attribute__((address_space(1))) void*)src,
          (__attribute__((address_space(3))) void*)&lds[8192 + (size_t)(c*256 + (wid << 6)) * 8], 16, 0, 0);
    }
    __syncthreads();

    bf16x8 bf[2][2];
#pragma unroll
    for (int s = 0; s < 2; ++s)
#pragma unroll
      for (int j = 0; j < 2; ++j) {
        const int n = wn + j*16 + (lane & 15);
        const int sl = (lane >> 4) ^ ((n >> 1) & 3);
        bf[s][j] = *(const bf16x8*)&lds[8192 + s*2048 + n*32 + sl*8];
      }
#pragma unroll
    for (int sa = 0; sa < 2; ++sa) {
      bf16x8 af[4];
#pragma unroll
      for (int i = 0; i < 4; ++i) {
        const int mrow = wm + i*16 + (lane & 15);
        const int sl = (lane >> 4) ^ ((mrow >> 1) & 3);
        af[i] = *(const bf16x8*)&lds[sa*4096 + mrow*32 + sl*8];
      }
#pragma unroll
      for (int sb = 0; sb < 2 - sa; ++sb)
#pragma unroll
        for (int i = 0; i < 4; ++i)
#pragma unroll
          for (int j = 0; j < 2; ++j)
            acc[i][j] = __builtin_amdgcn_mfma_f32_16x16x32_bf16(af[i], bf[sb][j], acc[i][j], 0, 0, 0);
    }
    __syncthreads();
  }
  // epilogue: store dw slab + fused w-weighted row partials
#pragma unroll
  for (int i = 0; i < 4; ++i) {
    const int rbase = wm + i*16 + ((lane >> 4) << 2);
#pragma unroll
    for (int r = 0; r < 4; ++r) {
      const int row = rbase + r;
      float s = 0.f;
#pragma unroll
      for (int j = 0; j < 2; ++j) {
        const int cg = n0 + wn + j*16 + (lane & 15);
        C[(size_t)row * NTR + cg] = acc[i][j][r];
        s = fmaf(w[(size_t)row * NTR + cg], acc[i][j][r], s);
      }
      rbuf[row][((wn >> 5) << 4) + (lane & 15)] = s;
    }
  }
  __syncthreads();
  if (tid < 128) {
    float s = 0.f;
#pragma unroll
    for (int t = 0; t < 32; ++t) s += rbuf[tid][t];
    rpart[((size_t)ks*256 + bn)*128 + tid] = s;
  }
}

// ---------------- Adam (reduces 512 rpart entries; u = 2 dw slabs) ----------------
__global__ __launch_bounds__(256) void k_adam_f(float* __restrict__ p,
    float* __restrict__ m, float* __restrict__ v,
    const float* __restrict__ w, const float* __restrict__ X,
    const float* __restrict__ rpart, float bc1, float bc2)
{
  const int bid = blockIdx.x, tid = threadIdx.x;
  const int row = bid >> 3;
  __shared__ float red[256];
  red[tid] = rpart[(size_t)tid*128 + row] + rpart[(size_t)(tid+256)*128 + row];
  __syncthreads();
  for (int s = 128; s > 0; s >>= 1) { if (tid < s) red[tid] += red[tid+s]; __syncthreads(); }
  const float rr = red[0];
  const size_t base = (size_t)bid * 2048 + tid * 4;
#pragma unroll
  for (int part = 0; part < 2; ++part) {
    const size_t off = base + part * 1024;
    float4 u  = *(const float4*)(X + off);
    const float4 u1 = *(const float4*)(X + (size_t)PN + off);
    u.x += u1.x; u.y += u1.y; u.z += u1.z; u.w += u1.w;
    const float4 w4 = *(const float4*)(w + off);
    const float wv[4] = {w4.x, w4.y, w4.z, w4.w};
    const float uu[4] = {u.x, u.y, u.z, u.w};
    float4 p4 = *(float4*)(p + off);
    float4 m4 = *(float4*)(m + off);
    float4 v4 = *(float4*)(v + off);
    float* pp = (float*)&p4; float* mm = (float*)&m4; float* vv = (float*)&v4;
#pragma unroll
    for (int e = 0; e < 4; ++e) {
      const float g  = wv[e] * (uu[e] - rr);
      const float mn = 0.9f*mm[e] + 0.1f*g;
      const float vn = 0.999f*vv[e] + 0.001f*(g*g);
      const float mh = mn / bc1, vh = vn / bc2;
      pp[e] = pp[e] - 1e-3f * mh / (sqrtf(vh) + 1e-8f);
      mm[e] = mn; vv[e] = vn;
    }
    *(float4*)(p + off) = p4;
    *(float4*)(m + off) = m4;
    *(float4*)(v + off) = v4;
  }
}

extern "C" void kernel_launch(void* const* d_in, const int* in_sizes, int n_in,
                              void* d_out, int out_size, void* d_ws, size_t ws_size,
                              hipStream_t stream) {
  const float* h = (const float*)d_in[0];
  const float* H = (const float*)d_in[1];
  (void)in_sizes; (void)n_in; (void)out_size; (void)ws_size;
  const int n_epoch = 1000;

  // floats: p,m,v (3PN) + w (PN) + X (4PN) + rpart (512*128)
  // ushorts: s-splits (2CN) + H-splits (2HN)   -> ~135 MB
  float* p  = (float*)d_ws;
  float* m  = p + PN;
  float* v  = m + PN;
  float* w  = v + PN;
  float* X  = w + PN;
  float* rp = X + (size_t)4*PN;        // 512*128
  ushort* s0 = (ushort*)(rp + 512*128);
  ushort* s1 = s0 + CN;
  ushort* H0 = s1 + CN, *H1 = H0 + HN;

  hipMemsetAsync(p, 0, (size_t)3*PN*sizeof(float), stream);
  k_prep<<<HN/1024, 256, 0, stream>>>(H, H0, H1);

  for (int s = 1; s <= n_epoch; ++s) {
    k_softmax_f<<<BB, 512, 0, stream>>>(p, w);
    k_fwd_v<<<dim3(8, FWD_SLABS), 256, 0, stream>>>(w, H, X);
    k_reduce_S2s<<<CN/512, 256, 0, stream>>>(X, h, s0, s1);
    k_gemm3_bwd<<<dim3(256, BWD_SLABS), 256, 0, stream>>>(s0, s1, H0, H1, w, X, rp);
    const float bc1 = 1.0f - powf(0.9f,   (float)s);
    const float bc2 = 1.0f - powf(0.999f, (float)s);
    k_adam_f<<<1024, 256, 0, stream>>>(p, m, v, w, X, rp, bc1, bc2);
  }
  k_softmax_f<<<BB, 512, 0, stream>>>(p, (float*)d_out);
}